// Round 16
// baseline (129.281 us; speedup 1.0000x reference)
//
#include <hip/hip_runtime.h>
#include <cmath>

// DotMaskLayer: B=16384, D=256, H=64, M=128.
// keep(j) = (j < K) | (128 <= j < 128+K)  [j=256 bias iff K>128; K<=128 in data]
// out[b,h] = tanh( sum_j keep(j)*Y[b,j]*W[b,j,h] ),  W = AUX.reshape(B,257,64)
//
// R16: R15 main kernel (nt loads/stores, predicated fetch, pre-masked X in
// LDS, contiguous per-wave ranges) + CLEAN LONGEST-FIRST SCHEDULING.
// R9's test was confounded: its scan was 1 thread x 129 dependent global
// round-trips (~90us serial latency). Here the scan is a parallel
// Hillis-Steele over one 256-thread block (~1us). Bucket order via atomics is
// racy -> affects scheduling only; each b is computed wholly by one block, so
// d_out is deterministic. counts/cursor/order fully rewritten every call.

#define D_DIM 256
#define H_DIM 64
#define ROWS 257
#define ROWSTRIDE (ROWS * H_DIM)   // 16448 floats per batch row of AUX

// ws layout (ints): [0,129) counts | [256,385) cursor | [512,512+B) order
#define WS_COUNTS 0
#define WS_CURSOR 256
#define WS_ORDER  512

typedef float vf4 __attribute__((ext_vector_type(4)));

__device__ __forceinline__ vf4 ldnt(const float* p)
{
    return __builtin_nontemporal_load(reinterpret_cast<const vf4*>(p));
}

__global__ void count_kernel(const int* __restrict__ K, int* __restrict__ counts, int B)
{
    const int i = blockIdx.x * 256 + threadIdx.x;
    if (i < B) atomicAdd(&counts[K[i]], 1);
}

// exclusive prefix over k = 128..0 (descending: largest k scheduled first)
__global__ void scan_kernel(const int* __restrict__ counts, int* __restrict__ cursor)
{
    __shared__ int s[256];
    const int t = threadIdx.x;                  // 0..255
    const int v = (t < 129) ? counts[128 - t] : 0;
    s[t] = v;
    __syncthreads();
    for (int off = 1; off < 256; off <<= 1) {
        const int x = (t >= off) ? s[t - off] : 0;
        __syncthreads();
        s[t] += x;
        __syncthreads();
    }
    if (t < 129) cursor[128 - t] = s[t] - v;    // exclusive
}

__global__ void scatter_kernel(const int* __restrict__ K, int* __restrict__ cursor,
                               int* __restrict__ order, int B)
{
    const int i = blockIdx.x * 256 + threadIdx.x;
    if (i < B) {
        const int p = atomicAdd(&cursor[K[i]], 1);
        order[p] = i;
    }
}

__global__ __launch_bounds__(256, 8)
void dotmask_kernel(const float* __restrict__ X,
                    const float* __restrict__ AUX,
                    const int* __restrict__ K,
                    const int* __restrict__ order,
                    float* __restrict__ out)
{
    const int b    = order[blockIdx.x];
    const int tid  = threadIdx.x;
    const int lane = tid & 63;
    const int w    = tid >> 6;          // wave id 0..3 (all share row b)
    const int jo   = lane >> 4;         // row offset within 4-row chunk
    const int h4   = (lane & 15) * 4;   // this lane's 4 consecutive h's

    const int k = K[b];
    const float* __restrict__ Wb  = AUX + (size_t)b * ROWSTRIDE;
    const float* __restrict__ WbH = Wb + h4;
    const float* __restrict__ Xb  = X   + (size_t)b * D_DIM;

    // ---- stage pre-masked X row into LDS (exec-masked load: kept only) ----
    __shared__ float xm[ROWS + 3];      // 257 used, padded
    {
        const bool keep = (tid < k) | ((tid >= 128) & (tid < 128 + k));
        float xv = 0.f;
        if (keep) xv = Xb[tid];         // masked lanes fetch nothing
        xm[tid] = xv;
        if (tid == 0) xm[256] = 0.f;
    }
    __syncthreads();

    float ax = 0.f, ay = 0.f, az = 0.f, aw = 0.f;

    // chunk c covers rows [4c,4c+4) + mirror (+128). Wave w owns contiguous
    // [lo, hi), hi-lo uniform +-1 across waves.
    const int C  = (k + 3) >> 2;
    const int lo = (C * w) >> 2;
    const int hi = (C * (w + 1)) >> 2;

    for (int c = lo; c < hi; c += 2) {
        // ---- chunk A: rows ja (side 1) and ja+128 (side 2), predicated ----
        const int ja = 4 * c + jo;
        if (ja < k) {                                  // => ja <= 127, ja+128 <= 255
            const vf4 wa1 = ldnt(WbH + ((size_t)ja         << 6));
            const vf4 wa2 = ldnt(WbH + ((size_t)(ja + 128) << 6));
            const float xa1 = xm[ja];
            const float xa2 = xm[ja + 128];
            ax += xa1 * wa1[0]; ay += xa1 * wa1[1]; az += xa1 * wa1[2]; aw += xa1 * wa1[3];
            ax += xa2 * wa2[0]; ay += xa2 * wa2[1]; az += xa2 * wa2[2]; aw += xa2 * wa2[3];
        }

        // ---- chunk B (wave-range guard + per-lane predication) ----
        if (c + 1 < hi) {
            const int jb = 4 * (c + 1) + jo;
            if (jb < k) {
                const vf4 wb1 = ldnt(WbH + ((size_t)jb         << 6));
                const vf4 wb2 = ldnt(WbH + ((size_t)(jb + 128) << 6));
                const float xb1 = xm[jb];
                const float xb2 = xm[jb + 128];
                ax += xb1 * wb1[0]; ay += xb1 * wb1[1]; az += xb1 * wb1[2]; aw += xb1 * wb1[3];
                ax += xb2 * wb2[0]; ay += xb2 * wb2[1]; az += xb2 * wb2[2]; aw += xb2 * wb2[3];
            }
        }
    }

    // bias row j=256 (kept iff k > 128; never with this data, kept for generality)
    if (k > 128 && w == 0 && jo == 0) {
        const vf4 wv = ldnt(Wb + (size_t)256 * H_DIM + h4);
        ax += wv[0]; ay += wv[1]; az += wv[2]; aw += wv[3];
    }

    // reduce across the 4 jo-groups (lanes l, l+16, l+32, l+48 share h4)
    ax += __shfl_xor(ax, 16); ay += __shfl_xor(ay, 16);
    az += __shfl_xor(az, 16); aw += __shfl_xor(aw, 16);
    ax += __shfl_xor(ax, 32); ay += __shfl_xor(ay, 32);
    az += __shfl_xor(az, 32); aw += __shfl_xor(aw, 32);

    // combine the 4 waves' partials via LDS
    __shared__ float red[4][H_DIM];
    if (lane < 16) {
        float4 p; p.x = ax; p.y = ay; p.z = az; p.w = aw;
        *reinterpret_cast<float4*>(&red[w][h4]) = p;
    }
    __syncthreads();

    if (tid < H_DIM) {
        const float s = red[0][tid] + red[1][tid] + red[2][tid] + red[3][tid];
        __builtin_nontemporal_store(tanhf(s), out + (size_t)b * H_DIM + tid);
    }
}

extern "C" void kernel_launch(void* const* d_in, const int* in_sizes, int n_in,
                              void* d_out, int out_size, void* d_ws, size_t ws_size,
                              hipStream_t stream)
{
    const float* X   = (const float*)d_in[0];
    const float* AUX = (const float*)d_in[1];
    const int*   K   = (const int*)d_in[2];
    float* out = (float*)d_out;
    int*   wsi = (int*)d_ws;

    const int B  = in_sizes[2];                // 16384
    const int nb = (B + 255) / 256;            // 64 blocks for the tiny passes

    hipMemsetAsync(wsi + WS_COUNTS, 0, 129 * sizeof(int), stream);
    count_kernel  <<<nb, 256, 0, stream>>>(K, wsi + WS_COUNTS, B);
    scan_kernel   <<<1, 256, 0, stream>>>(wsi + WS_COUNTS, wsi + WS_CURSOR);
    scatter_kernel<<<nb, 256, 0, stream>>>(K, wsi + WS_CURSOR, wsi + WS_ORDER, B);

    dotmask_kernel<<<B, 256, 0, stream>>>(X, AUX, K, wsi + WS_ORDER, out);
}

// Round 17
// 98.442 us; speedup vs baseline: 1.3133x; 1.3133x over previous
//
#include <hip/hip_runtime.h>
#include <cmath>

// DotMaskLayer: B=16384, D=256, H=64, M=128.
// keep(j) = (j < K) | (128 <= j < 128+K)  [j=256 bias iff K>128; K<=128 in data]
// out[b,h] = tanh( sum_j keep(j)*Y[b,j]*W[b,j,h] ),  W = AUX.reshape(B,257,64)
//
// FINAL (R15, 98.5us = 5.6 TB/s effective, ~89% of 6.29 TB/s copy ceiling):
//  - one 256-thread block per b; 4 waves split b's chunk list contiguously
//    (block time ~ single k; fixes E[max4 k] slot inflation, +15%)
//  - nontemporal W loads + out store (zero-reuse stream; bypassing cache
//    allocation churn was +11%)
//  - exec-mask predicated fetch (no tail/X over-fetch, ~-21 MB)
//  - pre-masked X staged in LDS (mask-free inner loop)
// Refuted by experiment: deeper ILP, chunk quantization, lockstep barriers,
// sequential/de-interleaved walks, VMEM-instruction halving, k-sorted
// scheduling (x2: address scatter costs ~30us >> drain gain <6us), uniform
// split (overhead > gain).

#define D_DIM 256
#define H_DIM 64
#define ROWS 257
#define ROWSTRIDE (ROWS * H_DIM)   // 16448 floats per batch row of AUX

typedef float vf4 __attribute__((ext_vector_type(4)));

__device__ __forceinline__ vf4 ldnt(const float* p)
{
    return __builtin_nontemporal_load(reinterpret_cast<const vf4*>(p));
}

__global__ __launch_bounds__(256, 8)
void dotmask_kernel(const float* __restrict__ X,
                    const float* __restrict__ AUX,
                    const int* __restrict__ K,
                    float* __restrict__ out)
{
    const int b    = blockIdx.x;
    const int tid  = threadIdx.x;
    const int lane = tid & 63;
    const int w    = tid >> 6;          // wave id 0..3 (all share row b)
    const int jo   = lane >> 4;         // row offset within 4-row chunk
    const int h4   = (lane & 15) * 4;   // this lane's 4 consecutive h's

    const int k = K[b];
    const float* __restrict__ Wb  = AUX + (size_t)b * ROWSTRIDE;
    const float* __restrict__ WbH = Wb + h4;
    const float* __restrict__ Xb  = X   + (size_t)b * D_DIM;

    // ---- stage pre-masked X row into LDS (exec-masked load: kept only) ----
    __shared__ float xm[ROWS + 3];      // 257 used, padded
    {
        const bool keep = (tid < k) | ((tid >= 128) & (tid < 128 + k));
        float xv = 0.f;
        if (keep) xv = Xb[tid];         // masked lanes fetch nothing
        xm[tid] = xv;
        if (tid == 0) xm[256] = 0.f;
    }
    __syncthreads();

    float ax = 0.f, ay = 0.f, az = 0.f, aw = 0.f;

    // chunk c covers rows [4c,4c+4) + mirror (+128). Wave w owns contiguous
    // [lo, hi), hi-lo uniform +-1 across waves.
    const int C  = (k + 3) >> 2;
    const int lo = (C * w) >> 2;
    const int hi = (C * (w + 1)) >> 2;

    for (int c = lo; c < hi; c += 2) {
        // ---- chunk A: rows ja (side 1) and ja+128 (side 2), predicated ----
        const int ja = 4 * c + jo;
        if (ja < k) {                                  // => ja <= 127, ja+128 <= 255
            const vf4 wa1 = ldnt(WbH + ((size_t)ja         << 6));
            const vf4 wa2 = ldnt(WbH + ((size_t)(ja + 128) << 6));
            const float xa1 = xm[ja];
            const float xa2 = xm[ja + 128];
            ax += xa1 * wa1[0]; ay += xa1 * wa1[1]; az += xa1 * wa1[2]; aw += xa1 * wa1[3];
            ax += xa2 * wa2[0]; ay += xa2 * wa2[1]; az += xa2 * wa2[2]; aw += xa2 * wa2[3];
        }

        // ---- chunk B (wave-range guard + per-lane predication) ----
        if (c + 1 < hi) {
            const int jb = 4 * (c + 1) + jo;
            if (jb < k) {
                const vf4 wb1 = ldnt(WbH + ((size_t)jb         << 6));
                const vf4 wb2 = ldnt(WbH + ((size_t)(jb + 128) << 6));
                const float xb1 = xm[jb];
                const float xb2 = xm[jb + 128];
                ax += xb1 * wb1[0]; ay += xb1 * wb1[1]; az += xb1 * wb1[2]; aw += xb1 * wb1[3];
                ax += xb2 * wb2[0]; ay += xb2 * wb2[1]; az += xb2 * wb2[2]; aw += xb2 * wb2[3];
            }
        }
    }

    // bias row j=256 (kept iff k > 128; never with this data, kept for generality)
    if (k > 128 && w == 0 && jo == 0) {
        const vf4 wv = ldnt(Wb + (size_t)256 * H_DIM + h4);
        ax += wv[0]; ay += wv[1]; az += wv[2]; aw += wv[3];
    }

    // reduce across the 4 jo-groups (lanes l, l+16, l+32, l+48 share h4)
    ax += __shfl_xor(ax, 16); ay += __shfl_xor(ay, 16);
    az += __shfl_xor(az, 16); aw += __shfl_xor(aw, 16);
    ax += __shfl_xor(ax, 32); ay += __shfl_xor(ay, 32);
    az += __shfl_xor(az, 32); aw += __shfl_xor(aw, 32);

    // combine the 4 waves' partials via LDS
    __shared__ float red[4][H_DIM];
    if (lane < 16) {
        float4 p; p.x = ax; p.y = ay; p.z = az; p.w = aw;
        *reinterpret_cast<float4*>(&red[w][h4]) = p;
    }
    __syncthreads();

    if (tid < H_DIM) {
        const float s = red[0][tid] + red[1][tid] + red[2][tid] + red[3][tid];
        __builtin_nontemporal_store(tanhf(s), out + (size_t)b * H_DIM + tid);
    }
}

extern "C" void kernel_launch(void* const* d_in, const int* in_sizes, int n_in,
                              void* d_out, int out_size, void* d_ws, size_t ws_size,
                              hipStream_t stream)
{
    const float* X   = (const float*)d_in[0];
    const float* AUX = (const float*)d_in[1];
    const int*   K   = (const int*)d_in[2];
    float* out = (float*)d_out;

    const int B = in_sizes[2];                 // 16384
    dotmask_kernel<<<B, 256, 0, stream>>>(X, AUX, K, out);
}